// Round 6
// baseline (4622.754 us; speedup 1.0000x reference)
//
#include <hip/hip_runtime.h>

#define EMB_DIM 64
#define BSHIFT 7
#define BROWS 128              // rows per bucket = 1 << BSHIFT
#define NB_MAX 2048
#define EPB 8192               // edges per partition block
#define PT 256                 // partition-kernel threads

static __device__ __forceinline__ unsigned long long pack_edge(int rl, int c, float v) {
    unsigned int lo = (unsigned int)c | ((unsigned int)rl << 24);   // col<2^24, rl<128
    return (unsigned long long)lo | ((unsigned long long)__float_as_uint(v) << 32);
}

// ---------- init: acc = x = concat(user, item) ----------
__global__ void lgcn_init(const float* __restrict__ user_w,
                          const float* __restrict__ item_w,
                          float* __restrict__ acc,
                          float* __restrict__ x,
                          int user_n4, int n4) {
    int i = blockIdx.x * blockDim.x + threadIdx.x;
    if (i >= n4) return;
    float4 v;
    if (i < user_n4) v = ((const float4*)user_w)[i];
    else             v = ((const float4*)item_w)[i - user_n4];
    ((float4*)acc)[i] = v;
    ((float4*)x)[i]   = v;
}

// ---------- pass 1: per-block bucket histogram (LDS) ----------
__global__ void k_hist_mat(const int* __restrict__ erow, int* __restrict__ mat,
                           int nb, long long nnz) {
    __shared__ int h[NB_MAX];
    int t = threadIdx.x;
    for (int b = t; b < nb; b += PT) h[b] = 0;
    __syncthreads();
    long long base = (long long)blockIdx.x * EPB;
    const int4* erow4 = (const int4*)erow;
    #pragma unroll
    for (int k = 0; k < EPB / PT / 4; ++k) {
        long long e = base + (long long)(k * PT + t) * 4;
        if (e + 4 <= nnz) {
            int4 r = erow4[e >> 2];
            atomicAdd(&h[r.x >> BSHIFT], 1);
            atomicAdd(&h[r.y >> BSHIFT], 1);
            atomicAdd(&h[r.z >> BSHIFT], 1);
            atomicAdd(&h[r.w >> BSHIFT], 1);
        } else {
            for (long long q = e; q < nnz; ++q) atomicAdd(&h[erow[q] >> BSHIFT], 1);
        }
    }
    __syncthreads();
    int* row = mat + (size_t)blockIdx.x * nb;
    for (int b = t; b < nb; b += PT) row[b] = h[b];
}

// ---------- pass 2: per-bucket exclusive scan over blocks (coalesced across threads) ----------
__global__ void k_scan_mat(int* __restrict__ mat, int* __restrict__ btotal,
                           int nb, int nblocks) {
    int b = blockIdx.x * blockDim.x + threadIdx.x;
    if (b >= nb) return;
    int run = 0;
    for (int j = 0; j < nblocks; ++j) {
        size_t idx = (size_t)j * nb + b;
        int v = mat[idx];
        mat[idx] = run;
        run += v;
    }
    btotal[b] = run;
}

// ---------- pass 3: exclusive scan over bucket totals (single block, nb<=2048) ----------
__global__ void k_scan_buckets(const int* __restrict__ btotal, int* __restrict__ bbase, int nb) {
    __shared__ int s[256];
    int t = threadIdx.x;
    int v[8]; int tot = 0;
    #pragma unroll
    for (int k = 0; k < 8; ++k) {
        int idx = t * 8 + k;
        v[k] = (idx < nb) ? btotal[idx] : 0;
        tot += v[k];
    }
    s[t] = tot; __syncthreads();
    for (int d = 1; d < 256; d <<= 1) {
        int add = (t >= d) ? s[t - d] : 0;
        __syncthreads(); s[t] += add; __syncthreads();
    }
    int off = s[t] - tot;
    #pragma unroll
    for (int k = 0; k < 8; ++k) {
        int idx = t * 8 + k;
        if (idx < nb) bbase[idx] = off;
        off += v[k];
    }
}

// ---------- pass 4: scatter into bucket-contiguous slots via LDS cursors ----------
__global__ void k_scatter2(const int* __restrict__ erow, const int* __restrict__ ecol,
                           const float* __restrict__ eval_, const int* __restrict__ mat,
                           const int* __restrict__ bbase,
                           unsigned long long* __restrict__ edges, int nb, long long nnz) {
    __shared__ int cur[NB_MAX];
    int t = threadIdx.x;
    const int* mrow = mat + (size_t)blockIdx.x * nb;
    for (int b = t; b < nb; b += PT) cur[b] = bbase[b] + mrow[b];
    __syncthreads();
    long long base = (long long)blockIdx.x * EPB;
    #pragma unroll
    for (int k = 0; k < EPB / PT / 4; ++k) {
        long long e = base + (long long)(k * PT + t) * 4;
        if (e + 4 <= nnz) {
            int4   r = ((const int4*)erow)[e >> 2];
            int4   c = ((const int4*)ecol)[e >> 2];
            float4 v = ((const float4*)eval_)[e >> 2];
            int p0 = atomicAdd(&cur[r.x >> BSHIFT], 1);
            int p1 = atomicAdd(&cur[r.y >> BSHIFT], 1);
            int p2 = atomicAdd(&cur[r.z >> BSHIFT], 1);
            int p3 = atomicAdd(&cur[r.w >> BSHIFT], 1);
            __builtin_nontemporal_store(pack_edge(r.x & (BROWS - 1), c.x, v.x), &edges[p0]);
            __builtin_nontemporal_store(pack_edge(r.y & (BROWS - 1), c.y, v.y), &edges[p1]);
            __builtin_nontemporal_store(pack_edge(r.z & (BROWS - 1), c.z, v.z), &edges[p2]);
            __builtin_nontemporal_store(pack_edge(r.w & (BROWS - 1), c.w, v.w), &edges[p3]);
        } else {
            for (long long q = e; q < nnz; ++q) {
                int r = erow[q];
                int p = atomicAdd(&cur[r >> BSHIFT], 1);
                edges[p] = pack_edge(r & (BROWS - 1), ecol[q], eval_[q]);
            }
        }
    }
}

// ---------- SpMM: one workgroup per bucket, LDS accumulator, fused layer-accumulate ----------
__global__ void __launch_bounds__(512, 2)
lgcn_spmm_bucket(const int* __restrict__ bbase, const int* __restrict__ btotal,
                 const unsigned long long* __restrict__ edges,
                 const float* __restrict__ x, float* __restrict__ y,
                 float* __restrict__ out, float scale, int is_last, int n) {
    __shared__ float accum[BROWS * EMB_DIM];   // 32 KB
    int t = threadIdx.x;
    int bkt = blockIdx.x;
    for (int i = t; i < BROWS * EMB_DIM; i += 512) accum[i] = 0.f;
    __syncthreads();
    int start = bbase[bkt];
    int m = btotal[bkt];
    int wave = t >> 6, lane = t & 63;
    int chunk = (m + 7) >> 3;                  // 8 waves
    int ws = start + wave * chunk;
    int we = min(start + m, ws + chunk);
    int j = ws;
    for (; j + 4 <= we; j += 4) {
        unsigned long long e0 = edges[j],     e1 = edges[j + 1];
        unsigned long long e2 = edges[j + 2], e3 = edges[j + 3];
        unsigned int l0 = (unsigned int)e0, l1 = (unsigned int)e1;
        unsigned int l2 = (unsigned int)e2, l3 = (unsigned int)e3;
        float x0 = x[(size_t)(l0 & 0xFFFFFFu) * EMB_DIM + lane];
        float x1 = x[(size_t)(l1 & 0xFFFFFFu) * EMB_DIM + lane];
        float x2 = x[(size_t)(l2 & 0xFFFFFFu) * EMB_DIM + lane];
        float x3 = x[(size_t)(l3 & 0xFFFFFFu) * EMB_DIM + lane];
        atomicAdd(&accum[((l0 >> 24) << 6) + lane], __uint_as_float((unsigned int)(e0 >> 32)) * x0);
        atomicAdd(&accum[((l1 >> 24) << 6) + lane], __uint_as_float((unsigned int)(e1 >> 32)) * x1);
        atomicAdd(&accum[((l2 >> 24) << 6) + lane], __uint_as_float((unsigned int)(e2 >> 32)) * x2);
        atomicAdd(&accum[((l3 >> 24) << 6) + lane], __uint_as_float((unsigned int)(e3 >> 32)) * x3);
    }
    for (; j < we; ++j) {
        unsigned long long e = edges[j];
        unsigned int lo = (unsigned int)e;
        float xv = x[(size_t)(lo & 0xFFFFFFu) * EMB_DIM + lane];
        atomicAdd(&accum[((lo >> 24) << 6) + lane], __uint_as_float((unsigned int)(e >> 32)) * xv);
    }
    __syncthreads();
    int r0 = bkt << BSHIFT;
    int nr = min(BROWS, n - r0);
    const float4* acc4 = (const float4*)accum;
    float4* y4 = (float4*)(y + (size_t)r0 * EMB_DIM);
    float4* o4 = (float4*)(out + (size_t)r0 * EMB_DIM);
    int tot4 = nr * (EMB_DIM / 4);
    for (int i = t; i < tot4; i += 512) {
        float4 a = acc4[i];
        float4 o = o4[i];
        o.x += a.x; o.y += a.y; o.z += a.z; o.w += a.w;
        if (is_last) { o.x *= scale; o.y *= scale; o.z *= scale; o.w *= scale; }
        y4[i] = a;
        o4[i] = o;
    }
}

extern "C" void kernel_launch(void* const* d_in, const int* in_sizes, int n_in,
                              void* d_out, int out_size, void* d_ws, size_t ws_size,
                              hipStream_t stream) {
    const float* user_w = (const float*)d_in[0];
    const float* item_w = (const float*)d_in[1];
    const int*   erow   = (const int*)d_in[2];
    const int*   ecol   = (const int*)d_in[3];
    const float* eval_  = (const float*)d_in[4];

    int n_users = in_sizes[0] / EMB_DIM;
    int n_items = in_sizes[1] / EMB_DIM;
    int n_total = n_users + n_items;
    long long nnz = in_sizes[2];

    int nb     = (n_total + BROWS - 1) >> BSHIFT;         // ~1172
    int nparts = (int)((nnz + EPB - 1) / EPB);            // ~489

    // workspace layout
    char* ws = (char*)d_ws;
    float* x      = (float*)ws;                 ws += (size_t)n_total * EMB_DIM * 4;
    float* y      = (float*)ws;                 ws += (size_t)n_total * EMB_DIM * 4;
    unsigned long long* edges = (unsigned long long*)ws; ws += (size_t)nnz * 8;
    int*   mat    = (int*)ws;                   ws += (size_t)nparts * nb * 4;
    int*   btotal = (int*)ws;                   ws += (size_t)nb * 4;
    int*   bbase  = (int*)ws;                   ws += (size_t)nb * 4;

    float* acc = (float*)d_out;
    int n4      = n_total * EMB_DIM / 4;
    int user_n4 = n_users * EMB_DIM / 4;

    lgcn_init<<<(n4 + 255) / 256, 256, 0, stream>>>(user_w, item_w, acc, x, user_n4, n4);

    k_hist_mat<<<nparts, PT, 0, stream>>>(erow, mat, nb, nnz);
    k_scan_mat<<<(nb + 255) / 256, 256, 0, stream>>>(mat, btotal, nb, nparts);
    k_scan_buckets<<<1, 256, 0, stream>>>(btotal, bbase, nb);
    k_scatter2<<<nparts, PT, 0, stream>>>(erow, ecol, eval_, mat, bbase, edges, nb, nnz);

    // 3 propagation layers, ping-pong x/y, accumulate into d_out
    float* xin = x;
    float* yout = y;
    for (int layer = 0; layer < 3; ++layer) {
        const bool last = (layer == 2);
        lgcn_spmm_bucket<<<nb, 512, 0, stream>>>(
            bbase, btotal, edges, xin, yout, acc, 0.25f, last ? 1 : 0, n_total);
        float* t = xin; xin = yout; yout = t;
    }
}

// Round 7
// 917.825 us; speedup vs baseline: 5.0366x; 5.0366x over previous
//
#include <hip/hip_runtime.h>

#define EMB_DIM 64
#define BSHIFT 7
#define BROWS 128              // rows per bucket
#define NB_MAX 2048
#define EPB 8192               // edges per partition block
#define PT 256                 // partition-kernel threads

// bucket-stage pack: col (18b) | row_local (7b) << 18 ; val in high 32
static __device__ __forceinline__ unsigned long long pack_b(int rl, int c, float v) {
    unsigned int lo = (unsigned int)c | ((unsigned int)rl << 18);
    return (unsigned long long)lo | ((unsigned long long)__float_as_uint(v) << 32);
}
// final CSR pack: col | val<<32
static __device__ __forceinline__ unsigned long long pack_e(unsigned int c, unsigned int vbits) {
    return (unsigned long long)c | ((unsigned long long)vbits << 32);
}

// ---------- init: acc = x = concat(user, item) ----------
__global__ void lgcn_init(const float* __restrict__ user_w,
                          const float* __restrict__ item_w,
                          float* __restrict__ acc,
                          float* __restrict__ x,
                          int user_n4, int n4) {
    int i = blockIdx.x * blockDim.x + threadIdx.x;
    if (i >= n4) return;
    float4 v;
    if (i < user_n4) v = ((const float4*)user_w)[i];
    else             v = ((const float4*)item_w)[i - user_n4];
    ((float4*)acc)[i] = v;
    ((float4*)x)[i]   = v;
}

// ---------- pass 1: per-block bucket histogram (LDS) ----------
__global__ void k_hist_mat(const int* __restrict__ erow, int* __restrict__ mat,
                           int nb, long long nnz) {
    __shared__ int h[NB_MAX];
    int t = threadIdx.x;
    for (int b = t; b < nb; b += PT) h[b] = 0;
    __syncthreads();
    long long base = (long long)blockIdx.x * EPB;
    const int4* erow4 = (const int4*)erow;
    #pragma unroll
    for (int k = 0; k < EPB / PT / 4; ++k) {
        long long e = base + (long long)(k * PT + t) * 4;
        if (e + 4 <= nnz) {
            int4 r = erow4[e >> 2];
            atomicAdd(&h[r.x >> BSHIFT], 1);
            atomicAdd(&h[r.y >> BSHIFT], 1);
            atomicAdd(&h[r.z >> BSHIFT], 1);
            atomicAdd(&h[r.w >> BSHIFT], 1);
        } else {
            for (long long q = e; q < nnz; ++q) atomicAdd(&h[erow[q] >> BSHIFT], 1);
        }
    }
    __syncthreads();
    int* row = mat + (size_t)blockIdx.x * nb;
    for (int b = t; b < nb; b += PT) row[b] = h[b];
}

// ---------- pass 2: per-bucket exclusive scan over blocks ----------
__global__ void k_scan_mat(int* __restrict__ mat, int* __restrict__ btotal,
                           int nb, int nblocks) {
    int b = blockIdx.x * blockDim.x + threadIdx.x;
    if (b >= nb) return;
    int run = 0;
    for (int j = 0; j < nblocks; ++j) {
        size_t idx = (size_t)j * nb + b;
        int v = mat[idx];
        mat[idx] = run;
        run += v;
    }
    btotal[b] = run;
}

// ---------- pass 3: exclusive scan over bucket totals ----------
__global__ void k_scan_buckets(const int* __restrict__ btotal, int* __restrict__ bbase, int nb) {
    __shared__ int s[256];
    int t = threadIdx.x;
    int v[8]; int tot = 0;
    #pragma unroll
    for (int k = 0; k < 8; ++k) {
        int idx = t * 8 + k;
        v[k] = (idx < nb) ? btotal[idx] : 0;
        tot += v[k];
    }
    s[t] = tot; __syncthreads();
    for (int d = 1; d < 256; d <<= 1) {
        int add = (t >= d) ? s[t - d] : 0;
        __syncthreads(); s[t] += add; __syncthreads();
    }
    int off = s[t] - tot;
    #pragma unroll
    for (int k = 0; k < 8; ++k) {
        int idx = t * 8 + k;
        if (idx < nb) bbase[idx] = off;
        off += v[k];
    }
}

// ---------- pass 4: scatter into bucket-clustered buffer via LDS cursors ----------
__global__ void k_scatter2(const int* __restrict__ erow, const int* __restrict__ ecol,
                           const float* __restrict__ eval_, const int* __restrict__ mat,
                           const int* __restrict__ bbase,
                           unsigned long long* __restrict__ ebuf, int nb, long long nnz) {
    __shared__ int cur[NB_MAX];
    int t = threadIdx.x;
    const int* mrow = mat + (size_t)blockIdx.x * nb;
    for (int b = t; b < nb; b += PT) cur[b] = bbase[b] + mrow[b];
    __syncthreads();
    long long base = (long long)blockIdx.x * EPB;
    #pragma unroll
    for (int k = 0; k < EPB / PT / 4; ++k) {
        long long e = base + (long long)(k * PT + t) * 4;
        if (e + 4 <= nnz) {
            int4   r = ((const int4*)erow)[e >> 2];
            int4   c = ((const int4*)ecol)[e >> 2];
            float4 v = ((const float4*)eval_)[e >> 2];
            int p0 = atomicAdd(&cur[r.x >> BSHIFT], 1);
            int p1 = atomicAdd(&cur[r.y >> BSHIFT], 1);
            int p2 = atomicAdd(&cur[r.z >> BSHIFT], 1);
            int p3 = atomicAdd(&cur[r.w >> BSHIFT], 1);
            __builtin_nontemporal_store(pack_b(r.x & (BROWS - 1), c.x, v.x), &ebuf[p0]);
            __builtin_nontemporal_store(pack_b(r.y & (BROWS - 1), c.y, v.y), &ebuf[p1]);
            __builtin_nontemporal_store(pack_b(r.z & (BROWS - 1), c.z, v.z), &ebuf[p2]);
            __builtin_nontemporal_store(pack_b(r.w & (BROWS - 1), c.w, v.w), &ebuf[p3]);
        } else {
            for (long long q = e; q < nnz; ++q) {
                int r = erow[q];
                int p = atomicAdd(&cur[r >> BSHIFT], 1);
                ebuf[p] = pack_b(r & (BROWS - 1), ecol[q], eval_[q]);
            }
        }
    }
}

// ---------- pass 5: per-bucket counting sort -> exact CSR (edges + row_ptr) ----------
__global__ void k_sort_bucket(const int* __restrict__ bbase, const int* __restrict__ btotal,
                              const unsigned long long* __restrict__ ebuf,
                              unsigned long long* __restrict__ edges,
                              int* __restrict__ row_ptr,
                              int nb, int n, long long nnz) {
    __shared__ int cnt[BROWS];
    __shared__ int sc[BROWS];
    __shared__ int cur[BROWS];
    int t = threadIdx.x;
    int bkt = blockIdx.x;
    if (t < BROWS) cnt[t] = 0;
    __syncthreads();
    int start = bbase[bkt];
    int m = btotal[bkt];
    // pass A: exact-row histogram
    for (int i = t; i < m; i += 256) {
        unsigned int lo = (unsigned int)ebuf[start + i];
        atomicAdd(&cnt[lo >> 18], 1);
    }
    __syncthreads();
    // inclusive scan of cnt over 128 entries
    if (t < BROWS) sc[t] = cnt[t];
    __syncthreads();
    for (int d = 1; d < BROWS; d <<= 1) {
        int v = (t < BROWS && t >= d) ? sc[t - d] : 0;
        __syncthreads();
        if (t < BROWS) sc[t] += v;
        __syncthreads();
    }
    int r0 = bkt << BSHIFT;
    if (t < BROWS) {
        int excl = sc[t] - cnt[t];
        cur[t] = start + excl;
        if (r0 + t < n) row_ptr[r0 + t] = start + excl;
    }
    if (t == 0 && bkt == nb - 1) row_ptr[n] = (int)nnz;
    __syncthreads();
    // pass B: scatter into exact row position
    for (int i = t; i < m; i += 256) {
        unsigned long long e = ebuf[start + i];
        unsigned int lo = (unsigned int)e;
        int p = atomicAdd(&cur[lo >> 18], 1);
        edges[p] = pack_e(lo & 0x3FFFFu, (unsigned int)(e >> 32));
    }
}

// ---------- CSR SpMM: one wave per row, lane = dim; fused layer-accumulate ----------
__global__ void lgcn_spmm_csr(const int* __restrict__ row_ptr,
                              const unsigned long long* __restrict__ edges,
                              const float* __restrict__ x,
                              float* __restrict__ y,
                              float* __restrict__ out,
                              float scale, int is_last, int n) {
    int w = (blockIdx.x * blockDim.x + threadIdx.x) >> 6;
    int lane = threadIdx.x & 63;
    if (w >= n) return;
    int start = row_ptr[w];
    int end   = row_ptr[w + 1];
    float acc = 0.f;
    int j = start;
    for (; j + 4 <= end; j += 4) {
        unsigned long long e0 = edges[j],     e1 = edges[j + 1];
        unsigned long long e2 = edges[j + 2], e3 = edges[j + 3];
        float x0 = x[(size_t)(unsigned int)e0 * EMB_DIM + lane];
        float x1 = x[(size_t)(unsigned int)e1 * EMB_DIM + lane];
        float x2 = x[(size_t)(unsigned int)e2 * EMB_DIM + lane];
        float x3 = x[(size_t)(unsigned int)e3 * EMB_DIM + lane];
        acc += __uint_as_float((unsigned int)(e0 >> 32)) * x0
             + __uint_as_float((unsigned int)(e1 >> 32)) * x1
             + __uint_as_float((unsigned int)(e2 >> 32)) * x2
             + __uint_as_float((unsigned int)(e3 >> 32)) * x3;
    }
    for (; j < end; ++j) {
        unsigned long long e = edges[j];
        acc += __uint_as_float((unsigned int)(e >> 32))
             * x[(size_t)(unsigned int)e * EMB_DIM + lane];
    }
    size_t oi = (size_t)w * EMB_DIM + lane;
    y[oi] = acc;
    float a = out[oi] + acc;
    out[oi] = is_last ? a * scale : a;
}

extern "C" void kernel_launch(void* const* d_in, const int* in_sizes, int n_in,
                              void* d_out, int out_size, void* d_ws, size_t ws_size,
                              hipStream_t stream) {
    const float* user_w = (const float*)d_in[0];
    const float* item_w = (const float*)d_in[1];
    const int*   erow   = (const int*)d_in[2];
    const int*   ecol   = (const int*)d_in[3];
    const float* eval_  = (const float*)d_in[4];

    int n_users = in_sizes[0] / EMB_DIM;
    int n_items = in_sizes[1] / EMB_DIM;
    int n_total = n_users + n_items;
    long long nnz = in_sizes[2];

    int nb     = (n_total + BROWS - 1) >> BSHIFT;
    int nparts = (int)((nnz + EPB - 1) / EPB);

    // workspace layout (ebuf aliases y: dead before first spmm writes y)
    char* ws = (char*)d_ws;
    float* x      = (float*)ws;                 ws += (size_t)n_total * EMB_DIM * 4;
    float* y      = (float*)ws;                 ws += (size_t)n_total * EMB_DIM * 4;
    unsigned long long* ebuf  = (unsigned long long*)y;   // alias
    unsigned long long* edges = (unsigned long long*)ws; ws += (size_t)nnz * 8;
    int*   mat    = (int*)ws;                   ws += (size_t)nparts * nb * 4;
    int*   btotal = (int*)ws;                   ws += (size_t)nb * 4;
    int*   bbase  = (int*)ws;                   ws += (size_t)nb * 4;
    int*   row_ptr= (int*)ws;                   ws += (size_t)(n_total + 1) * 4;

    float* acc = (float*)d_out;
    int n4      = n_total * EMB_DIM / 4;
    int user_n4 = n_users * EMB_DIM / 4;

    lgcn_init<<<(n4 + 255) / 256, 256, 0, stream>>>(user_w, item_w, acc, x, user_n4, n4);

    k_hist_mat<<<nparts, PT, 0, stream>>>(erow, mat, nb, nnz);
    k_scan_mat<<<(nb + 255) / 256, 256, 0, stream>>>(mat, btotal, nb, nparts);
    k_scan_buckets<<<1, 256, 0, stream>>>(btotal, bbase, nb);
    k_scatter2<<<nparts, PT, 0, stream>>>(erow, ecol, eval_, mat, bbase, ebuf, nb, nnz);
    k_sort_bucket<<<nb, 256, 0, stream>>>(bbase, btotal, ebuf, edges, row_ptr, nb, n_total, nnz);

    // 3 propagation layers, ping-pong x/y, accumulate into d_out
    float* xin = x;
    float* yout = y;
    for (int layer = 0; layer < 3; ++layer) {
        const bool last = (layer == 2);
        int blocks = (n_total * 64 + 255) / 256;
        lgcn_spmm_csr<<<blocks, 256, 0, stream>>>(
            row_ptr, edges, xin, yout, acc, 0.25f, last ? 1 : 0, n_total);
        float* t = xin; xin = yout; yout = t;
    }
}

// Round 8
// 856.394 us; speedup vs baseline: 5.3979x; 1.0717x over previous
//
#include <hip/hip_runtime.h>

#define EMB_DIM 64
#define BSHIFT 7
#define BROWS 128              // rows per bucket
#define NB_MAX 2048
#define EPB 8192               // edges per partition block
#define PT 256                 // partition-kernel threads

// bucket-stage pack: col (18b) | row_local (7b) << 18 ; val in high 32
static __device__ __forceinline__ unsigned long long pack_b(int rl, int c, float v) {
    unsigned int lo = (unsigned int)c | ((unsigned int)rl << 18);
    return (unsigned long long)lo | ((unsigned long long)__float_as_uint(v) << 32);
}
// final CSR pack: col | val<<32
static __device__ __forceinline__ unsigned long long pack_e(unsigned int c, unsigned int vbits) {
    return (unsigned long long)c | ((unsigned long long)vbits << 32);
}

static __device__ __forceinline__ unsigned short f2bf(float f) {   // RNE
    unsigned int u = __float_as_uint(f);
    return (unsigned short)((u + 0x7FFFu + ((u >> 16) & 1u)) >> 16);
}
static __device__ __forceinline__ float bf2f(unsigned short b) {
    return __uint_as_float((unsigned int)b << 16);
}

// ---------- init: acc(fp32) = concat(user,item); x(bf16) = same ----------
__global__ void lgcn_init(const float* __restrict__ user_w,
                          const float* __restrict__ item_w,
                          float* __restrict__ acc,
                          unsigned short* __restrict__ x,
                          int user_n4, int n4) {
    int i = blockIdx.x * blockDim.x + threadIdx.x;
    if (i >= n4) return;
    float4 v;
    if (i < user_n4) v = ((const float4*)user_w)[i];
    else             v = ((const float4*)item_w)[i - user_n4];
    ((float4*)acc)[i] = v;
    ushort4 b;
    b.x = f2bf(v.x); b.y = f2bf(v.y); b.z = f2bf(v.z); b.w = f2bf(v.w);
    ((ushort4*)x)[i] = b;
}

// ---------- pass 1: per-block bucket histogram (LDS) ----------
__global__ void k_hist_mat(const int* __restrict__ erow, int* __restrict__ mat,
                           int nb, long long nnz) {
    __shared__ int h[NB_MAX];
    int t = threadIdx.x;
    for (int b = t; b < nb; b += PT) h[b] = 0;
    __syncthreads();
    long long base = (long long)blockIdx.x * EPB;
    const int4* erow4 = (const int4*)erow;
    #pragma unroll
    for (int k = 0; k < EPB / PT / 4; ++k) {
        long long e = base + (long long)(k * PT + t) * 4;
        if (e + 4 <= nnz) {
            int4 r = erow4[e >> 2];
            atomicAdd(&h[r.x >> BSHIFT], 1);
            atomicAdd(&h[r.y >> BSHIFT], 1);
            atomicAdd(&h[r.z >> BSHIFT], 1);
            atomicAdd(&h[r.w >> BSHIFT], 1);
        } else {
            for (long long q = e; q < nnz; ++q) atomicAdd(&h[erow[q] >> BSHIFT], 1);
        }
    }
    __syncthreads();
    int* row = mat + (size_t)blockIdx.x * nb;
    for (int b = t; b < nb; b += PT) row[b] = h[b];
}

// ---------- pass 2: per-bucket exclusive scan over blocks ----------
__global__ void k_scan_mat(int* __restrict__ mat, int* __restrict__ btotal,
                           int nb, int nblocks) {
    int b = blockIdx.x * blockDim.x + threadIdx.x;
    if (b >= nb) return;
    int run = 0;
    for (int j = 0; j < nblocks; ++j) {
        size_t idx = (size_t)j * nb + b;
        int v = mat[idx];
        mat[idx] = run;
        run += v;
    }
    btotal[b] = run;
}

// ---------- pass 3: exclusive scan over bucket totals ----------
__global__ void k_scan_buckets(const int* __restrict__ btotal, int* __restrict__ bbase, int nb) {
    __shared__ int s[256];
    int t = threadIdx.x;
    int v[8]; int tot = 0;
    #pragma unroll
    for (int k = 0; k < 8; ++k) {
        int idx = t * 8 + k;
        v[k] = (idx < nb) ? btotal[idx] : 0;
        tot += v[k];
    }
    s[t] = tot; __syncthreads();
    for (int d = 1; d < 256; d <<= 1) {
        int add = (t >= d) ? s[t - d] : 0;
        __syncthreads(); s[t] += add; __syncthreads();
    }
    int off = s[t] - tot;
    #pragma unroll
    for (int k = 0; k < 8; ++k) {
        int idx = t * 8 + k;
        if (idx < nb) bbase[idx] = off;
        off += v[k];
    }
}

// ---------- pass 4: scatter into bucket-clustered buffer via LDS cursors ----------
__global__ void k_scatter2(const int* __restrict__ erow, const int* __restrict__ ecol,
                           const float* __restrict__ eval_, const int* __restrict__ mat,
                           const int* __restrict__ bbase,
                           unsigned long long* __restrict__ ebuf, int nb, long long nnz) {
    __shared__ int cur[NB_MAX];
    int t = threadIdx.x;
    const int* mrow = mat + (size_t)blockIdx.x * nb;
    for (int b = t; b < nb; b += PT) cur[b] = bbase[b] + mrow[b];
    __syncthreads();
    long long base = (long long)blockIdx.x * EPB;
    #pragma unroll
    for (int k = 0; k < EPB / PT / 4; ++k) {
        long long e = base + (long long)(k * PT + t) * 4;
        if (e + 4 <= nnz) {
            int4   r = ((const int4*)erow)[e >> 2];
            int4   c = ((const int4*)ecol)[e >> 2];
            float4 v = ((const float4*)eval_)[e >> 2];
            int p0 = atomicAdd(&cur[r.x >> BSHIFT], 1);
            int p1 = atomicAdd(&cur[r.y >> BSHIFT], 1);
            int p2 = atomicAdd(&cur[r.z >> BSHIFT], 1);
            int p3 = atomicAdd(&cur[r.w >> BSHIFT], 1);
            __builtin_nontemporal_store(pack_b(r.x & (BROWS - 1), c.x, v.x), &ebuf[p0]);
            __builtin_nontemporal_store(pack_b(r.y & (BROWS - 1), c.y, v.y), &ebuf[p1]);
            __builtin_nontemporal_store(pack_b(r.z & (BROWS - 1), c.z, v.z), &ebuf[p2]);
            __builtin_nontemporal_store(pack_b(r.w & (BROWS - 1), c.w, v.w), &ebuf[p3]);
        } else {
            for (long long q = e; q < nnz; ++q) {
                int r = erow[q];
                int p = atomicAdd(&cur[r >> BSHIFT], 1);
                ebuf[p] = pack_b(r & (BROWS - 1), ecol[q], eval_[q]);
            }
        }
    }
}

// ---------- pass 5: per-bucket counting sort -> exact CSR (edges + row_ptr) ----------
__global__ void k_sort_bucket(const int* __restrict__ bbase, const int* __restrict__ btotal,
                              const unsigned long long* __restrict__ ebuf,
                              unsigned long long* __restrict__ edges,
                              int* __restrict__ row_ptr,
                              int nb, int n, long long nnz) {
    __shared__ int cnt[BROWS];
    __shared__ int sc[BROWS];
    __shared__ int cur[BROWS];
    int t = threadIdx.x;
    int bkt = blockIdx.x;
    if (t < BROWS) cnt[t] = 0;
    __syncthreads();
    int start = bbase[bkt];
    int m = btotal[bkt];
    for (int i = t; i < m; i += 256) {
        unsigned int lo = (unsigned int)ebuf[start + i];
        atomicAdd(&cnt[lo >> 18], 1);
    }
    __syncthreads();
    if (t < BROWS) sc[t] = cnt[t];
    __syncthreads();
    for (int d = 1; d < BROWS; d <<= 1) {
        int v = (t < BROWS && t >= d) ? sc[t - d] : 0;
        __syncthreads();
        if (t < BROWS) sc[t] += v;
        __syncthreads();
    }
    int r0 = bkt << BSHIFT;
    if (t < BROWS) {
        int excl = sc[t] - cnt[t];
        cur[t] = start + excl;
        if (r0 + t < n) row_ptr[r0 + t] = start + excl;
    }
    if (t == 0 && bkt == nb - 1) row_ptr[n] = (int)nnz;
    __syncthreads();
    for (int i = t; i < m; i += 256) {
        unsigned long long e = ebuf[start + i];
        unsigned int lo = (unsigned int)e;
        int p = atomicAdd(&cur[lo >> 18], 1);
        edges[p] = pack_e(lo & 0x3FFFFu, (unsigned int)(e >> 32));
    }
}

// ---------- CSR SpMM: one wave per row, lane = dim; bf16 gather, fp32 acc ----------
__global__ void lgcn_spmm_csr(const int* __restrict__ row_ptr,
                              const unsigned long long* __restrict__ edges,
                              const unsigned short* __restrict__ x,
                              unsigned short* __restrict__ y,
                              float* __restrict__ out,
                              float scale, int is_last, int n) {
    int w = (blockIdx.x * blockDim.x + threadIdx.x) >> 6;
    int lane = threadIdx.x & 63;
    if (w >= n) return;
    int start = row_ptr[w];
    int end   = row_ptr[w + 1];
    float acc = 0.f;
    int j = start;
    for (; j + 4 <= end; j += 4) {
        unsigned long long e0 = edges[j],     e1 = edges[j + 1];
        unsigned long long e2 = edges[j + 2], e3 = edges[j + 3];
        unsigned short u0 = x[(size_t)(unsigned int)e0 * EMB_DIM + lane];
        unsigned short u1 = x[(size_t)(unsigned int)e1 * EMB_DIM + lane];
        unsigned short u2 = x[(size_t)(unsigned int)e2 * EMB_DIM + lane];
        unsigned short u3 = x[(size_t)(unsigned int)e3 * EMB_DIM + lane];
        acc += __uint_as_float((unsigned int)(e0 >> 32)) * bf2f(u0)
             + __uint_as_float((unsigned int)(e1 >> 32)) * bf2f(u1)
             + __uint_as_float((unsigned int)(e2 >> 32)) * bf2f(u2)
             + __uint_as_float((unsigned int)(e3 >> 32)) * bf2f(u3);
    }
    for (; j < end; ++j) {
        unsigned long long e = edges[j];
        acc += __uint_as_float((unsigned int)(e >> 32))
             * bf2f(x[(size_t)(unsigned int)e * EMB_DIM + lane]);
    }
    size_t oi = (size_t)w * EMB_DIM + lane;
    y[oi] = f2bf(acc);
    float a = out[oi] + acc;
    out[oi] = is_last ? a * scale : a;
}

extern "C" void kernel_launch(void* const* d_in, const int* in_sizes, int n_in,
                              void* d_out, int out_size, void* d_ws, size_t ws_size,
                              hipStream_t stream) {
    const float* user_w = (const float*)d_in[0];
    const float* item_w = (const float*)d_in[1];
    const int*   erow   = (const int*)d_in[2];
    const int*   ecol   = (const int*)d_in[3];
    const float* eval_  = (const float*)d_in[4];

    int n_users = in_sizes[0] / EMB_DIM;
    int n_items = in_sizes[1] / EMB_DIM;
    int n_total = n_users + n_items;
    long long nnz = in_sizes[2];

    int nb     = (n_total + BROWS - 1) >> BSHIFT;
    int nparts = (int)((nnz + EPB - 1) / EPB);

    // workspace layout
    char* ws = (char*)d_ws;
    unsigned short* x = (unsigned short*)ws;    ws += (size_t)n_total * EMB_DIM * 2;
    unsigned short* y = (unsigned short*)ws;    ws += (size_t)n_total * EMB_DIM * 2;
    unsigned long long* ebuf  = (unsigned long long*)ws; ws += (size_t)nnz * 8;
    unsigned long long* edges = (unsigned long long*)ws; ws += (size_t)nnz * 8;
    int*   mat    = (int*)ws;                   ws += (size_t)nparts * nb * 4;
    int*   btotal = (int*)ws;                   ws += (size_t)nb * 4;
    int*   bbase  = (int*)ws;                   ws += (size_t)nb * 4;
    int*   row_ptr= (int*)ws;                   ws += (size_t)(n_total + 1) * 4;

    float* acc = (float*)d_out;
    int n4      = n_total * EMB_DIM / 4;
    int user_n4 = n_users * EMB_DIM / 4;

    lgcn_init<<<(n4 + 255) / 256, 256, 0, stream>>>(user_w, item_w, acc, x, user_n4, n4);

    k_hist_mat<<<nparts, PT, 0, stream>>>(erow, mat, nb, nnz);
    k_scan_mat<<<(nb + 255) / 256, 256, 0, stream>>>(mat, btotal, nb, nparts);
    k_scan_buckets<<<1, 256, 0, stream>>>(btotal, bbase, nb);
    k_scatter2<<<nparts, PT, 0, stream>>>(erow, ecol, eval_, mat, bbase, ebuf, nb, nnz);
    k_sort_bucket<<<nb, 256, 0, stream>>>(bbase, btotal, ebuf, edges, row_ptr, nb, n_total, nnz);

    // 3 propagation layers, ping-pong x/y, accumulate into d_out
    unsigned short* xin = x;
    unsigned short* yout = y;
    for (int layer = 0; layer < 3; ++layer) {
        const bool last = (layer == 2);
        int blocks = (n_total * 64 + 255) / 256;
        lgcn_spmm_csr<<<blocks, 256, 0, stream>>>(
            row_ptr, edges, xin, yout, acc, 0.25f, last ? 1 : 0, n_total);
        unsigned short* t = xin; xin = yout; yout = t;
    }
}